// Round 1
// baseline (2460.265 us; speedup 1.0000x reference)
//
#include <hip/hip_runtime.h>
#include <math.h>

// Problem constants
#define NQ 16384        // B*H*W = 16*32*32 query rows
#define DD 512          // feature dim
#define MM 2000         // memory slots
#define BB 16
#define HH 32
#define WW 32

// d_out layout (floats, concatenated in return order)
#define UQ_OFF   0            // updated_query  (16,1024,32,32) = 16777216
#define UM_OFF   16777216     // updated_memory (2000,512)      = 1024000
#define SQ_OFF   17801216     // score_query    (16384,2000)    = 32768000
#define SM_OFF   50569216     // score_memory   (16384,2000)    = 32768000
#define SEP_OFF  83337216     // separateness_loss scalar
#define COMP_OFF 83337217     // compactness_loss scalar

// Static device workspace (avoids any dependence on ws_size).
// All buffers are fully (re)written every call before being read.
__device__ float    g_qf[NQ * DD];        // normalized query rows (n,d) row-major
__device__ float    g_keyshat[MM * DD];   // unit-normalized keys
__device__ float    g_invn[NQ];           // 1/||query row||
__device__ int      g_top1[NQ];
__device__ int      g_top2[NQ];
__device__ unsigned g_colmax[MM];         // bits of max exp((s-1)*10) per column (positive floats)
__device__ float    g_colsum[MM];         // sum  exp((s-1)*10) per column
__device__ float    g_wraw[NQ];
__device__ float    g_denom[MM];          // segment sum of w_raw
__device__ float    g_bins[128];          // [0:64) separateness partials, [64:128) compactness

// ---------------------------------------------------------------- init
__global__ __launch_bounds__(256) void init_kernel() {
    int i = blockIdx.x * 256 + threadIdx.x;
    if (i < MM) { g_colsum[i] = 0.f; g_denom[i] = 0.f; g_colmax[i] = 0u; }
    if (i < 128) g_bins[i] = 0.f;
}

// ---------------------------------------------------------------- keys normalize
__global__ __launch_bounds__(256) void keys_norm_kernel(const float* __restrict__ keys) {
    int m = blockIdx.x, t = threadIdx.x;
    float v0 = keys[m * DD + t], v1 = keys[m * DD + t + 256];
    __shared__ float red[256];
    red[t] = v0 * v0 + v1 * v1;
    __syncthreads();
    for (int s = 128; s > 0; s >>= 1) { if (t < s) red[t] += red[t + s]; __syncthreads(); }
    float inv = 1.f / fmaxf(sqrtf(red[0]), 1e-12f);
    g_keyshat[m * DD + t]       = v0 * inv;
    g_keyshat[m * DD + t + 256] = v1 * inv;
}

// ---------------------------------------------------------------- query normalize -> qf (n,d) + invn
// block per (b,h); coalesced reads of query[b,d,h,:]; LDS transpose for coalesced qf writes
__global__ __launch_bounds__(256) void qnorm_kernel(const float* __restrict__ q) {
    int bh = blockIdx.x; int b = bh >> 5, h = bh & 31;
    int t = threadIdx.x; int w = t & 31, dl = t >> 5;   // w lane, d-group
    const float* qb = q + (size_t)b * DD * 1024 + h * 32;

    float ss = 0.f;
    for (int d = dl; d < DD; d += 8) { float v = qb[d * 1024 + w]; ss = fmaf(v, v, ss); }
    __shared__ float red[8][32];
    __shared__ float sinv[32];
    red[dl][w] = ss;
    __syncthreads();
    if (dl == 0) {
        float tot = 0.f;
        #pragma unroll
        for (int j = 0; j < 8; ++j) tot += red[j][w];
        float inv = 1.f / fmaxf(sqrtf(tot), 1e-12f);
        sinv[w] = inv;
        g_invn[b * 1024 + h * 32 + w] = inv;
    }
    __syncthreads();

    __shared__ float tile[32][33];
    int dcol = t & 31, wl = t >> 5;
    for (int d0 = 0; d0 < DD; d0 += 32) {
        for (int dd = dl; dd < 32; dd += 8)
            tile[dd][w] = qb[(d0 + dd) * 1024 + w] * sinv[w];
        __syncthreads();
        for (int wr = wl; wr < 32; wr += 8)
            g_qf[((size_t)b * 1024 + h * 32 + wr) * DD + d0 + dcol] = tile[dcol][wr];
        __syncthreads();
    }
}

// ---------------------------------------------------------------- updated_query first half (= qf in NCHW layout)
__global__ __launch_bounds__(256) void qf_out_kernel(const float* __restrict__ q, float* __restrict__ out) {
    int e0 = blockIdx.x * 1024 + threadIdx.x;
    #pragma unroll
    for (int i = 0; i < 4; ++i) {
        int e = e0 + i * 256;                      // < 16*512*1024 = 2^23
        int b = e >> 19;                           // 512*1024 = 2^19
        int rem = e & ((1 << 19) - 1);
        int c = rem >> 10, r = rem & 1023;
        out[UQ_OFF + (size_t)(b * 1024 + c) * 1024 + r] = q[e] * g_invn[b * 1024 + r];
    }
}

// ---------------------------------------------------------------- GEMM1: raw score = qf @ keys_hat^T -> out[SQ slot]
// A (NQ x DD) row-major, B^T layout (MM x DD) row-major. 128x128 tile, 8x8/thread.
__global__ __launch_bounds__(256) void gemm1_kernel(float* __restrict__ out) {
    __shared__ float As[16][132];
    __shared__ float Bs[16][132];
    int t = threadIdx.x;
    int tx = t & 15, ty = t >> 4;
    int row0 = blockIdx.x * 128;
    int col0 = blockIdx.y * 128;
    float c[8][8] = {};

    for (int k0 = 0; k0 < DD; k0 += 16) {
        #pragma unroll
        for (int p = 0; p < 8; ++p) {
            int lin = t + p * 256;
            int m = lin >> 4, k = lin & 15;
            As[k][m] = g_qf[(size_t)(row0 + m) * DD + k0 + k];
        }
        #pragma unroll
        for (int p = 0; p < 8; ++p) {
            int lin = t + p * 256;
            int n = lin >> 4, k = lin & 15;
            int gc = col0 + n;
            Bs[k][n] = (gc < MM) ? g_keyshat[(size_t)gc * DD + k0 + k] : 0.f;
        }
        __syncthreads();
        #pragma unroll
        for (int kk = 0; kk < 16; ++kk) {
            float a[8], b[8];
            *(float4*)&a[0] = ((const float4*)&As[kk][ty * 8])[0];
            *(float4*)&a[4] = ((const float4*)&As[kk][ty * 8])[1];
            *(float4*)&b[0] = ((const float4*)&Bs[kk][tx * 8])[0];
            *(float4*)&b[4] = ((const float4*)&Bs[kk][tx * 8])[1];
            #pragma unroll
            for (int i = 0; i < 8; ++i)
                #pragma unroll
                for (int j = 0; j < 8; ++j)
                    c[i][j] = fmaf(a[i], b[j], c[i][j]);
        }
        __syncthreads();
    }
    if (col0 + tx * 8 < MM) {   // MM % 8 == 0 -> per-thread column group fully in or out
        #pragma unroll
        for (int i = 0; i < 8; ++i) {
            size_t base = SQ_OFF + (size_t)(row0 + ty * 8 + i) * MM + col0 + tx * 8;
            *(float4*)&out[base]     = make_float4(c[i][0], c[i][1], c[i][2], c[i][3]);
            *(float4*)&out[base + 4] = make_float4(c[i][4], c[i][5], c[i][6], c[i][7]);
        }
    }
}

// ---------------------------------------------------------------- row softmax (temp .1) + top2 -> SM slot, g_top1/2
__global__ __launch_bounds__(256) void row_softmax_kernel(float* __restrict__ out) {
    int n = blockIdx.x, t = threadIdx.x;
    __shared__ float buf[MM];
    __shared__ float rv[256], rv2[256];
    __shared__ int   ri[256], ri2[256];

    const float* raw = out + SQ_OFF + (size_t)n * MM;
    float v1 = -3.0e38f, v2 = -3.0e38f; int i1 = 0x7fffffff, i2 = 0x7fffffff;
    #pragma unroll
    for (int i = 0; i < 8; ++i) {
        int idx = i * 256 + t;
        if (idx < MM) {
            float v = raw[idx];
            buf[idx] = v;
            if (v > v1)      { v2 = v1; i2 = i1; v1 = v; i1 = idx; }
            else if (v > v2) { v2 = v; i2 = idx; }
        }
    }
    rv[t] = v1; ri[t] = i1; rv2[t] = v2; ri2[t] = i2;
    __syncthreads();
    for (int s = 128; s > 0; s >>= 1) {
        if (t < s) {
            float av1 = rv[t],  bv1 = rv[t + s];
            float av2 = rv2[t], bv2 = rv2[t + s];
            int   ai1 = ri[t],  bi1 = ri[t + s];
            int   ai2 = ri2[t], bi2 = ri2[t + s];
            bool afirst = (av1 > bv1) || (av1 == bv1 && ai1 < bi1);
            float nv1, nv2; int ni1, ni2;
            if (afirst) {
                nv1 = av1; ni1 = ai1;
                if ((av2 > bv1) || (av2 == bv1 && ai2 < bi1)) { nv2 = av2; ni2 = ai2; }
                else                                          { nv2 = bv1; ni2 = bi1; }
            } else {
                nv1 = bv1; ni1 = bi1;
                if ((bv2 > av1) || (bv2 == av1 && bi2 < ai1)) { nv2 = bv2; ni2 = bi2; }
                else                                          { nv2 = av1; ni2 = ai1; }
            }
            rv[t] = nv1; ri[t] = ni1; rv2[t] = nv2; ri2[t] = ni2;
        }
        __syncthreads();
    }
    float rowmax = rv[0];
    if (t == 0) { g_top1[n] = ri[0]; g_top2[n] = ri2[0]; }
    __syncthreads();   // everyone done reading rv[0] before reuse

    float lsum = 0.f;
    #pragma unroll
    for (int i = 0; i < 8; ++i) {
        int idx = i * 256 + t;
        if (idx < MM) {
            float e = expf((buf[idx] - rowmax) * 10.0f);
            buf[idx] = e;
            lsum += e;
        }
    }
    rv[t] = lsum;
    __syncthreads();
    for (int s = 128; s > 0; s >>= 1) { if (t < s) rv[t] += rv[t + s]; __syncthreads(); }
    float inv = 1.f / rv[0];
    float* sm = out + SM_OFF + (size_t)n * MM;
    #pragma unroll
    for (int i = 0; i < 8; ++i) {
        int idx = i * 256 + t;
        if (idx < MM) sm[idx] = buf[idx] * inv;
    }
}

// ---------------------------------------------------------------- column stats: max & sum of exp((s-1)*10)
__global__ __launch_bounds__(256) void col_stats_kernel(const float* __restrict__ out) {
    int m = blockIdx.x * 256 + threadIdx.x;
    if (m >= MM) return;
    int n0 = blockIdx.y * 256;
    const float* raw = out + SQ_OFF;
    float lmax = 0.f, lsum = 0.f;
    for (int i = 0; i < 256; ++i) {
        float v = raw[(size_t)(n0 + i) * MM + m];
        float e = expf((v - 1.0f) * 10.0f);   // shift-invariant: |s| <= 1
        lmax = fmaxf(lmax, e);
        lsum += e;
    }
    atomicMax(&g_colmax[m], __float_as_uint(lmax));   // positive floats: bit order == value order
    atomicAdd(&g_colsum[m], lsum);
}

// ---------------------------------------------------------------- score_query = exp((s-1)*10)/colsum (in-place on SQ slot)
__global__ __launch_bounds__(256) void score_query_kernel(float* __restrict__ out) {
    int m = blockIdx.x * 256 + threadIdx.x;
    if (m >= MM) return;
    int n0 = blockIdx.y * 8;
    float inv = 1.f / g_colsum[m];
    float* raw = out + SQ_OFF;
    #pragma unroll
    for (int i = 0; i < 8; ++i) {
        size_t idx = (size_t)(n0 + i) * MM + m;
        raw[idx] = expf((raw[idx] - 1.0f) * 10.0f) * inv;
    }
}

// ---------------------------------------------------------------- w_raw + denom segment sum
__global__ __launch_bounds__(256) void wraw_kernel(const float* __restrict__ out) {
    int n = blockIdx.x * 256 + threadIdx.x;
    int gi = g_top1[n];
    float sqv = out[SQ_OFF + (size_t)n * MM + gi];
    float cm = __uint_as_float(g_colmax[gi]) / g_colsum[gi];
    float w = sqv / (cm + 1e-8f);
    g_wraw[n] = w;
    atomicAdd(&g_denom[gi], w);
}

// ---------------------------------------------------------------- updated_memory: segment weighted sum + keys, l2norm
__global__ __launch_bounds__(256) void seg_update_kernel(const float* __restrict__ keys, float* __restrict__ out) {
    int m = blockIdx.x, t = threadIdx.x;
    __shared__ int   sh_g[256];
    __shared__ float sh_w[256];
    float invd = 1.f / (g_denom[m] + 1e-8f);
    float acc0 = 0.f, acc1 = 0.f;
    for (int c = 0; c < NQ; c += 256) {
        sh_g[t] = g_top1[c + t];
        sh_w[t] = g_wraw[c + t];
        __syncthreads();
        for (int i = 0; i < 256; ++i) {
            if (sh_g[i] == m) {
                float wgt = sh_w[i] * invd;
                acc0 = fmaf(wgt, g_qf[(size_t)(c + i) * DD + t], acc0);
                acc1 = fmaf(wgt, g_qf[(size_t)(c + i) * DD + t + 256], acc1);
            }
        }
        __syncthreads();
    }
    float v0 = acc0 + keys[m * DD + t];
    float v1 = acc1 + keys[m * DD + t + 256];
    __shared__ float red[256];
    red[t] = v0 * v0 + v1 * v1;
    __syncthreads();
    for (int s = 128; s > 0; s >>= 1) { if (t < s) red[t] += red[t + s]; __syncthreads(); }
    float inv = 1.f / fmaxf(sqrtf(red[0]), 1e-12f);
    out[UM_OFF + (size_t)m * DD + t]       = v0 * inv;
    out[UM_OFF + (size_t)m * DD + t + 256] = v1 * inv;
}

// ---------------------------------------------------------------- GEMM2: concat = score_memory @ keys -> updated_query 2nd half
// A (NQ x MM) row-major from SM slot, B (MM x DD) row-major. 128x128 tile, 8x8/thread. No edge guards (all divisible).
__global__ __launch_bounds__(256) void gemm2_kernel(const float* __restrict__ keys, float* __restrict__ out) {
    __shared__ float As[16][132];
    __shared__ float Bs[16][132];
    int t = threadIdx.x;
    int tx = t & 15, ty = t >> 4;
    int row0 = blockIdx.x * 128;
    int col0 = blockIdx.y * 128;
    const float* A = out + SM_OFF;
    float c[8][8] = {};

    for (int k0 = 0; k0 < MM; k0 += 16) {
        #pragma unroll
        for (int p = 0; p < 8; ++p) {
            int lin = t + p * 256;
            int m = lin >> 4, k = lin & 15;
            As[k][m] = A[(size_t)(row0 + m) * MM + k0 + k];
        }
        #pragma unroll
        for (int p = 0; p < 8; ++p) {
            int lin = t + p * 256;
            int j = lin & 127, k = lin >> 7;
            Bs[k][j] = keys[(size_t)(k0 + k) * DD + col0 + j];
        }
        __syncthreads();
        #pragma unroll
        for (int kk = 0; kk < 16; ++kk) {
            float a[8], b[8];
            *(float4*)&a[0] = ((const float4*)&As[kk][ty * 8])[0];
            *(float4*)&a[4] = ((const float4*)&As[kk][ty * 8])[1];
            *(float4*)&b[0] = ((const float4*)&Bs[kk][tx * 8])[0];
            *(float4*)&b[4] = ((const float4*)&Bs[kk][tx * 8])[1];
            #pragma unroll
            for (int i = 0; i < 8; ++i)
                #pragma unroll
                for (int j = 0; j < 8; ++j)
                    c[i][j] = fmaf(a[i], b[j], c[i][j]);
        }
        __syncthreads();
    }
    // write transposed into updated_query[b, 512+col, h, w]; rows of this block share the same b
    int bq = row0 >> 10;
    int rbase = (row0 & 1023) + ty * 8;
    #pragma unroll
    for (int j = 0; j < 8; ++j) {
        int col = col0 + tx * 8 + j;
        size_t o = UQ_OFF + (size_t)(bq * 1024 + 512 + col) * 1024 + rbase;
        *(float4*)&out[o]     = make_float4(c[0][j], c[1][j], c[2][j], c[3][j]);
        *(float4*)&out[o + 4] = make_float4(c[4][j], c[5][j], c[6][j], c[7][j]);
    }
}

// ---------------------------------------------------------------- losses
__global__ __launch_bounds__(256) void loss_kernel(const float* __restrict__ keys) {
    int n = blockIdx.x, t = threadIdx.x;
    int gi = g_top1[n], ni = g_top2[n];
    float q0 = g_qf[(size_t)n * DD + t],      q1 = g_qf[(size_t)n * DD + t + 256];
    float p0 = keys[gi * DD + t],             p1 = keys[gi * DD + t + 256];
    float e0 = keys[ni * DD + t],             e1 = keys[ni * DD + t + 256];
    float dq0 = q0 - p0, dq1 = q1 - p1;
    float comp = dq0 * dq0 + dq1 * dq1;
    float a0 = dq0 + 1e-6f, a1 = dq1 + 1e-6f;
    float dpp = a0 * a0 + a1 * a1;
    float b0 = q0 - e0 + 1e-6f, b1 = q1 - e1 + 1e-6f;
    float dnn = b0 * b0 + b1 * b1;
    __shared__ float r1[256], r2[256], r3[256];
    r1[t] = comp; r2[t] = dpp; r3[t] = dnn;
    __syncthreads();
    for (int s = 128; s > 0; s >>= 1) {
        if (t < s) { r1[t] += r1[t + s]; r2[t] += r2[t + s]; r3[t] += r3[t + s]; }
        __syncthreads();
    }
    if (t == 0) {
        float dp = sqrtf(r2[0]), dn = sqrtf(r3[0]);
        float sep = fmaxf(dp - dn + 1.0f, 0.0f);
        atomicAdd(&g_bins[n & 63], sep);
        atomicAdd(&g_bins[64 + (n & 63)], r1[0]);
    }
}

__global__ __launch_bounds__(64) void finalize_kernel(float* __restrict__ out) {
    if (threadIdx.x == 0) {
        float s = 0.f, c = 0.f;
        for (int i = 0; i < 64; ++i) { s += g_bins[i]; c += g_bins[64 + i]; }
        out[SEP_OFF]  = s / (float)NQ;
        out[COMP_OFF] = c / ((float)NQ * (float)DD);
    }
}

// ---------------------------------------------------------------- launch
extern "C" void kernel_launch(void* const* d_in, const int* in_sizes, int n_in,
                              void* d_out, int out_size, void* d_ws, size_t ws_size,
                              hipStream_t stream) {
    const float* query = (const float*)d_in[0];
    const float* keys  = (const float*)d_in[1];
    float* out = (float*)d_out;

    init_kernel<<<dim3(8), dim3(256), 0, stream>>>();
    keys_norm_kernel<<<dim3(MM), dim3(256), 0, stream>>>(keys);
    qnorm_kernel<<<dim3(512), dim3(256), 0, stream>>>(query);
    qf_out_kernel<<<dim3(8192), dim3(256), 0, stream>>>(query, out);
    gemm1_kernel<<<dim3(128, 16), dim3(256), 0, stream>>>(out);
    row_softmax_kernel<<<dim3(NQ), dim3(256), 0, stream>>>(out);
    col_stats_kernel<<<dim3(8, 64), dim3(256), 0, stream>>>(out);
    score_query_kernel<<<dim3(8, 2048), dim3(256), 0, stream>>>(out);
    wraw_kernel<<<dim3(64), dim3(256), 0, stream>>>(out);
    seg_update_kernel<<<dim3(MM), dim3(256), 0, stream>>>(keys, out);
    gemm2_kernel<<<dim3(128, 4), dim3(256), 0, stream>>>(keys, out);
    loss_kernel<<<dim3(NQ), dim3(256), 0, stream>>>(keys);
    finalize_kernel<<<dim3(1), dim3(64), 0, stream>>>(out);
}

// Round 2
// 1603.176 us; speedup vs baseline: 1.5346x; 1.5346x over previous
//
#include <hip/hip_runtime.h>
#include <math.h>

// Problem constants
#define NQ 16384        // B*H*W = 16*32*32 query rows
#define DD 512          // feature dim
#define MM 2000         // memory slots

// d_out layout (floats, concatenated in return order)
#define UQ_OFF   0            // updated_query  (16,1024,32,32) = 16777216
#define UM_OFF   16777216     // updated_memory (2000,512)      = 1024000
#define SQ_OFF   17801216     // score_query    (16384,2000)    = 32768000
#define SM_OFF   50569216     // score_memory   (16384,2000)    = 32768000
#define SEP_OFF  83337216     // separateness_loss scalar
#define COMP_OFF 83337217     // compactness_loss scalar

// Static device workspace. All buffers fully (re)written every call before read.
__device__ float    g_qf[NQ * DD];        // normalized query rows (n,d) row-major
__device__ float    g_keyshat[MM * DD];   // unit-normalized keys
__device__ float    g_invn[NQ];           // 1/||query row||
__device__ int      g_top1[NQ];
__device__ int      g_top2[NQ];
__device__ unsigned g_colmax[MM];         // bits of max exp((s-1)*10) per column
__device__ float    g_colsum[MM];         // sum  exp((s-1)*10) per column
__device__ float    g_wraw[NQ];
__device__ float    g_denom[MM];          // segment sum of w_raw
__device__ float    g_bins[128];          // [0:64) separateness partials, [64:128) compactness
// CSR inversion of g = top1 mapping
__device__ int      g_cnt[MM];
__device__ int      g_cursor[MM];
__device__ int      g_base[MM];
__device__ int      g_rows[NQ];
__device__ float    g_wvals[NQ];

// ---------------------------------------------------------------- init
__global__ __launch_bounds__(256) void init_kernel() {
    int i = blockIdx.x * 256 + threadIdx.x;
    if (i < MM) { g_colsum[i] = 0.f; g_denom[i] = 0.f; g_colmax[i] = 0u;
                  g_cnt[i] = 0; g_cursor[i] = 0; }
    if (i < 128) g_bins[i] = 0.f;
}

// ---------------------------------------------------------------- keys normalize
__global__ __launch_bounds__(256) void keys_norm_kernel(const float* __restrict__ keys) {
    int m = blockIdx.x, t = threadIdx.x;
    float v0 = keys[m * DD + t], v1 = keys[m * DD + t + 256];
    __shared__ float red[256];
    red[t] = v0 * v0 + v1 * v1;
    __syncthreads();
    for (int s = 128; s > 0; s >>= 1) { if (t < s) red[t] += red[t + s]; __syncthreads(); }
    float inv = 1.f / fmaxf(sqrtf(red[0]), 1e-12f);
    g_keyshat[m * DD + t]       = v0 * inv;
    g_keyshat[m * DD + t + 256] = v1 * inv;
}

// ---------------------------------------------------------------- query normalize -> qf (n,d) + invn
__global__ __launch_bounds__(256) void qnorm_kernel(const float* __restrict__ q) {
    int bh = blockIdx.x; int b = bh >> 5, h = bh & 31;
    int t = threadIdx.x; int w = t & 31, dl = t >> 5;
    const float* qb = q + (size_t)b * DD * 1024 + h * 32;

    float ss = 0.f;
    for (int d = dl; d < DD; d += 8) { float v = qb[d * 1024 + w]; ss = fmaf(v, v, ss); }
    __shared__ float red[8][32];
    __shared__ float sinv[32];
    red[dl][w] = ss;
    __syncthreads();
    if (dl == 0) {
        float tot = 0.f;
        #pragma unroll
        for (int j = 0; j < 8; ++j) tot += red[j][w];
        float inv = 1.f / fmaxf(sqrtf(tot), 1e-12f);
        sinv[w] = inv;
        g_invn[b * 1024 + h * 32 + w] = inv;
    }
    __syncthreads();

    __shared__ float tile[32][33];
    int dcol = t & 31, wl = t >> 5;
    for (int d0 = 0; d0 < DD; d0 += 32) {
        for (int dd = dl; dd < 32; dd += 8)
            tile[dd][w] = qb[(d0 + dd) * 1024 + w] * sinv[w];
        __syncthreads();
        for (int wr = wl; wr < 32; wr += 8)
            g_qf[((size_t)b * 1024 + h * 32 + wr) * DD + d0 + dcol] = tile[dcol][wr];
        __syncthreads();
    }
}

// ---------------------------------------------------------------- updated_query first half
__global__ __launch_bounds__(256) void qf_out_kernel(const float* __restrict__ q, float* __restrict__ out) {
    int e0 = blockIdx.x * 1024 + threadIdx.x;
    #pragma unroll
    for (int i = 0; i < 4; ++i) {
        int e = e0 + i * 256;
        int b = e >> 19;
        int rem = e & ((1 << 19) - 1);
        int c = rem >> 10, r = rem & 1023;
        out[UQ_OFF + (size_t)(b * 1024 + c) * 1024 + r] = q[e] * g_invn[b * 1024 + r];
    }
}

// ---------------------------------------------------------------- GEMM1: raw score = qf @ keys_hat^T -> SQ slot
__global__ __launch_bounds__(256) void gemm1_kernel(float* __restrict__ out) {
    __shared__ float As[16][132];
    __shared__ float Bs[16][132];
    int t = threadIdx.x;
    int tx = t & 15, ty = t >> 4;
    int row0 = blockIdx.x * 128;
    int col0 = blockIdx.y * 128;
    float c[8][8] = {};

    for (int k0 = 0; k0 < DD; k0 += 16) {
        #pragma unroll
        for (int p = 0; p < 8; ++p) {
            int lin = t + p * 256;
            int m = lin >> 4, k = lin & 15;
            As[k][m] = g_qf[(size_t)(row0 + m) * DD + k0 + k];
        }
        #pragma unroll
        for (int p = 0; p < 8; ++p) {
            int lin = t + p * 256;
            int n = lin >> 4, k = lin & 15;
            int gc = col0 + n;
            Bs[k][n] = (gc < MM) ? g_keyshat[(size_t)gc * DD + k0 + k] : 0.f;
        }
        __syncthreads();
        #pragma unroll
        for (int kk = 0; kk < 16; ++kk) {
            float a[8], b[8];
            *(float4*)&a[0] = ((const float4*)&As[kk][ty * 8])[0];
            *(float4*)&a[4] = ((const float4*)&As[kk][ty * 8])[1];
            *(float4*)&b[0] = ((const float4*)&Bs[kk][tx * 8])[0];
            *(float4*)&b[4] = ((const float4*)&Bs[kk][tx * 8])[1];
            #pragma unroll
            for (int i = 0; i < 8; ++i)
                #pragma unroll
                for (int j = 0; j < 8; ++j)
                    c[i][j] = fmaf(a[i], b[j], c[i][j]);
        }
        __syncthreads();
    }
    if (col0 + tx * 8 < MM) {
        #pragma unroll
        for (int i = 0; i < 8; ++i) {
            size_t base = SQ_OFF + (size_t)(row0 + ty * 8 + i) * MM + col0 + tx * 8;
            *(float4*)&out[base]     = make_float4(c[i][0], c[i][1], c[i][2], c[i][3]);
            *(float4*)&out[base + 4] = make_float4(c[i][4], c[i][5], c[i][6], c[i][7]);
        }
    }
}

// ---------------------------------------------------------------- row softmax (temp .1) + top2
__global__ __launch_bounds__(256) void row_softmax_kernel(float* __restrict__ out) {
    int n = blockIdx.x, t = threadIdx.x;
    __shared__ float buf[MM];
    __shared__ float rv[256], rv2[256];
    __shared__ int   ri[256], ri2[256];

    const float* raw = out + SQ_OFF + (size_t)n * MM;
    float v1 = -3.0e38f, v2 = -3.0e38f; int i1 = 0x7fffffff, i2 = 0x7fffffff;
    #pragma unroll
    for (int i = 0; i < 8; ++i) {
        int idx = i * 256 + t;
        if (idx < MM) {
            float v = raw[idx];
            buf[idx] = v;
            if (v > v1)      { v2 = v1; i2 = i1; v1 = v; i1 = idx; }
            else if (v > v2) { v2 = v; i2 = idx; }
        }
    }
    rv[t] = v1; ri[t] = i1; rv2[t] = v2; ri2[t] = i2;
    __syncthreads();
    for (int s = 128; s > 0; s >>= 1) {
        if (t < s) {
            float av1 = rv[t],  bv1 = rv[t + s];
            float av2 = rv2[t], bv2 = rv2[t + s];
            int   ai1 = ri[t],  bi1 = ri[t + s];
            int   ai2 = ri2[t], bi2 = ri2[t + s];
            bool afirst = (av1 > bv1) || (av1 == bv1 && ai1 < bi1);
            float nv1, nv2; int ni1, ni2;
            if (afirst) {
                nv1 = av1; ni1 = ai1;
                if ((av2 > bv1) || (av2 == bv1 && ai2 < bi1)) { nv2 = av2; ni2 = ai2; }
                else                                          { nv2 = bv1; ni2 = bi1; }
            } else {
                nv1 = bv1; ni1 = bi1;
                if ((bv2 > av1) || (bv2 == av1 && bi2 < ai1)) { nv2 = bv2; ni2 = bi2; }
                else                                          { nv2 = av1; ni2 = ai1; }
            }
            rv[t] = nv1; ri[t] = ni1; rv2[t] = nv2; ri2[t] = ni2;
        }
        __syncthreads();
    }
    float rowmax = rv[0];
    if (t == 0) { g_top1[n] = ri[0]; g_top2[n] = ri2[0]; }
    __syncthreads();

    float lsum = 0.f;
    #pragma unroll
    for (int i = 0; i < 8; ++i) {
        int idx = i * 256 + t;
        if (idx < MM) {
            float e = expf((buf[idx] - rowmax) * 10.0f);
            buf[idx] = e;
            lsum += e;
        }
    }
    rv[t] = lsum;
    __syncthreads();
    for (int s = 128; s > 0; s >>= 1) { if (t < s) rv[t] += rv[t + s]; __syncthreads(); }
    float inv = 1.f / rv[0];
    float* sm = out + SM_OFF + (size_t)n * MM;
    #pragma unroll
    for (int i = 0; i < 8; ++i) {
        int idx = i * 256 + t;
        if (idx < MM) sm[idx] = buf[idx] * inv;
    }
}

// ---------------------------------------------------------------- column stats: max & sum of exp((s-1)*10)
__global__ __launch_bounds__(256) void col_stats_kernel(const float* __restrict__ out) {
    int m = blockIdx.x * 256 + threadIdx.x;
    if (m >= MM) return;
    int n0 = blockIdx.y * 256;
    const float* raw = out + SQ_OFF;
    float lmax = 0.f, lsum = 0.f;
    for (int i = 0; i < 256; ++i) {
        float v = raw[(size_t)(n0 + i) * MM + m];
        float e = expf((v - 1.0f) * 10.0f);
        lmax = fmaxf(lmax, e);
        lsum += e;
    }
    atomicMax(&g_colmax[m], __float_as_uint(lmax));
    atomicAdd(&g_colsum[m], lsum);
}

// ---------------------------------------------------------------- score_query = exp((s-1)*10)/colsum
__global__ __launch_bounds__(256) void score_query_kernel(float* __restrict__ out) {
    int m = blockIdx.x * 256 + threadIdx.x;
    if (m >= MM) return;
    int n0 = blockIdx.y * 8;
    float inv = 1.f / g_colsum[m];
    float* raw = out + SQ_OFF;
    #pragma unroll
    for (int i = 0; i < 8; ++i) {
        size_t idx = (size_t)(n0 + i) * MM + m;
        raw[idx] = expf((raw[idx] - 1.0f) * 10.0f) * inv;
    }
}

// ---------------------------------------------------------------- w_raw + denom + per-slot counts
__global__ __launch_bounds__(256) void wraw_kernel(const float* __restrict__ out) {
    int n = blockIdx.x * 256 + threadIdx.x;
    int gi = g_top1[n];
    float sqv = out[SQ_OFF + (size_t)n * MM + gi];
    float cm = __uint_as_float(g_colmax[gi]) / g_colsum[gi];
    float w = sqv / (cm + 1e-8f);
    g_wraw[n] = w;
    atomicAdd(&g_denom[gi], w);
    atomicAdd(&g_cnt[gi], 1);
}

// ---------------------------------------------------------------- exclusive scan of g_cnt -> g_base (1 block)
__global__ __launch_bounds__(256) void scan_kernel() {
    int t = threadIdx.x;
    __shared__ int chunk[256];
    __shared__ int off[256];
    int loc[8];
    int s = 0;
    #pragma unroll
    for (int i = 0; i < 8; ++i) {
        int idx = t * 8 + i;
        int c = (idx < MM) ? g_cnt[idx] : 0;
        loc[i] = s; s += c;
    }
    chunk[t] = s;
    __syncthreads();
    if (t == 0) {
        int acc = 0;
        for (int i = 0; i < 256; ++i) { off[i] = acc; acc += chunk[i]; }
    }
    __syncthreads();
    #pragma unroll
    for (int i = 0; i < 8; ++i) {
        int idx = t * 8 + i;
        if (idx < MM) g_base[idx] = off[t] + loc[i];
    }
}

// ---------------------------------------------------------------- scatter rows into CSR
__global__ __launch_bounds__(256) void scatter_kernel() {
    int n = blockIdx.x * 256 + threadIdx.x;
    int gi = g_top1[n];
    int pos = atomicAdd(&g_cursor[gi], 1);
    int dst = g_base[gi] + pos;
    g_rows[dst]  = n;
    g_wvals[dst] = g_wraw[n];
}

// ---------------------------------------------------------------- updated_memory via CSR lists
__global__ __launch_bounds__(256) void seg_update_kernel(const float* __restrict__ keys, float* __restrict__ out) {
    int m = blockIdx.x, t = threadIdx.x;
    int start = g_base[m], cnt = g_cnt[m];
    float invd = 1.f / (g_denom[m] + 1e-8f);
    float acc0 = 0.f, acc1 = 0.f;
    for (int i = 0; i < cnt; ++i) {
        int   row = g_rows[start + i];       // block-uniform -> L1 broadcast
        float wgt = g_wvals[start + i] * invd;
        acc0 = fmaf(wgt, g_qf[(size_t)row * DD + t],       acc0);
        acc1 = fmaf(wgt, g_qf[(size_t)row * DD + t + 256], acc1);
    }
    float v0 = acc0 + keys[m * DD + t];
    float v1 = acc1 + keys[m * DD + t + 256];
    __shared__ float red[256];
    red[t] = v0 * v0 + v1 * v1;
    __syncthreads();
    for (int s = 128; s > 0; s >>= 1) { if (t < s) red[t] += red[t + s]; __syncthreads(); }
    float inv = 1.f / fmaxf(sqrtf(red[0]), 1e-12f);
    out[UM_OFF + (size_t)m * DD + t]       = v0 * inv;
    out[UM_OFF + (size_t)m * DD + t + 256] = v1 * inv;
}

// ---------------------------------------------------------------- GEMM2: concat = score_memory @ keys
__global__ __launch_bounds__(256) void gemm2_kernel(const float* __restrict__ keys, float* __restrict__ out) {
    __shared__ float As[16][132];
    __shared__ float Bs[16][132];
    int t = threadIdx.x;
    int tx = t & 15, ty = t >> 4;
    int row0 = blockIdx.x * 128;
    int col0 = blockIdx.y * 128;
    const float* A = out + SM_OFF;
    float c[8][8] = {};

    for (int k0 = 0; k0 < MM; k0 += 16) {
        #pragma unroll
        for (int p = 0; p < 8; ++p) {
            int lin = t + p * 256;
            int m = lin >> 4, k = lin & 15;
            As[k][m] = A[(size_t)(row0 + m) * MM + k0 + k];
        }
        #pragma unroll
        for (int p = 0; p < 8; ++p) {
            int lin = t + p * 256;
            int j = lin & 127, k = lin >> 7;
            Bs[k][j] = keys[(size_t)(k0 + k) * DD + col0 + j];
        }
        __syncthreads();
        #pragma unroll
        for (int kk = 0; kk < 16; ++kk) {
            float a[8], b[8];
            *(float4*)&a[0] = ((const float4*)&As[kk][ty * 8])[0];
            *(float4*)&a[4] = ((const float4*)&As[kk][ty * 8])[1];
            *(float4*)&b[0] = ((const float4*)&Bs[kk][tx * 8])[0];
            *(float4*)&b[4] = ((const float4*)&Bs[kk][tx * 8])[1];
            #pragma unroll
            for (int i = 0; i < 8; ++i)
                #pragma unroll
                for (int j = 0; j < 8; ++j)
                    c[i][j] = fmaf(a[i], b[j], c[i][j]);
        }
        __syncthreads();
    }
    int bq = row0 >> 10;
    int rbase = (row0 & 1023) + ty * 8;
    #pragma unroll
    for (int j = 0; j < 8; ++j) {
        int col = col0 + tx * 8 + j;
        size_t o = UQ_OFF + (size_t)(bq * 1024 + 512 + col) * 1024 + rbase;
        *(float4*)&out[o]     = make_float4(c[0][j], c[1][j], c[2][j], c[3][j]);
        *(float4*)&out[o + 4] = make_float4(c[4][j], c[5][j], c[6][j], c[7][j]);
    }
}

// ---------------------------------------------------------------- losses
__global__ __launch_bounds__(256) void loss_kernel(const float* __restrict__ keys) {
    int n = blockIdx.x, t = threadIdx.x;
    int gi = g_top1[n], ni = g_top2[n];
    float q0 = g_qf[(size_t)n * DD + t],      q1 = g_qf[(size_t)n * DD + t + 256];
    float p0 = keys[gi * DD + t],             p1 = keys[gi * DD + t + 256];
    float e0 = keys[ni * DD + t],             e1 = keys[ni * DD + t + 256];
    float dq0 = q0 - p0, dq1 = q1 - p1;
    float comp = dq0 * dq0 + dq1 * dq1;
    float a0 = dq0 + 1e-6f, a1 = dq1 + 1e-6f;
    float dpp = a0 * a0 + a1 * a1;
    float b0 = q0 - e0 + 1e-6f, b1 = q1 - e1 + 1e-6f;
    float dnn = b0 * b0 + b1 * b1;
    __shared__ float r1[256], r2[256], r3[256];
    r1[t] = comp; r2[t] = dpp; r3[t] = dnn;
    __syncthreads();
    for (int s = 128; s > 0; s >>= 1) {
        if (t < s) { r1[t] += r1[t + s]; r2[t] += r2[t + s]; r3[t] += r3[t + s]; }
        __syncthreads();
    }
    if (t == 0) {
        float dp = sqrtf(r2[0]), dn = sqrtf(r3[0]);
        float sep = fmaxf(dp - dn + 1.0f, 0.0f);
        atomicAdd(&g_bins[n & 63], sep);
        atomicAdd(&g_bins[64 + (n & 63)], r1[0]);
    }
}

__global__ __launch_bounds__(64) void finalize_kernel(float* __restrict__ out) {
    if (threadIdx.x == 0) {
        float s = 0.f, c = 0.f;
        for (int i = 0; i < 64; ++i) { s += g_bins[i]; c += g_bins[64 + i]; }
        out[SEP_OFF]  = s / (float)NQ;
        out[COMP_OFF] = c / ((float)NQ * (float)DD);
    }
}

// ---------------------------------------------------------------- launch
extern "C" void kernel_launch(void* const* d_in, const int* in_sizes, int n_in,
                              void* d_out, int out_size, void* d_ws, size_t ws_size,
                              hipStream_t stream) {
    const float* query = (const float*)d_in[0];
    const float* keys  = (const float*)d_in[1];
    float* out = (float*)d_out;

    init_kernel<<<dim3(8), dim3(256), 0, stream>>>();
    keys_norm_kernel<<<dim3(MM), dim3(256), 0, stream>>>(keys);
    qnorm_kernel<<<dim3(512), dim3(256), 0, stream>>>(query);
    qf_out_kernel<<<dim3(8192), dim3(256), 0, stream>>>(query, out);
    gemm1_kernel<<<dim3(128, 16), dim3(256), 0, stream>>>(out);
    row_softmax_kernel<<<dim3(NQ), dim3(256), 0, stream>>>(out);
    col_stats_kernel<<<dim3(8, 64), dim3(256), 0, stream>>>(out);
    score_query_kernel<<<dim3(8, 2048), dim3(256), 0, stream>>>(out);
    wraw_kernel<<<dim3(64), dim3(256), 0, stream>>>(out);
    scan_kernel<<<dim3(1), dim3(256), 0, stream>>>();
    scatter_kernel<<<dim3(64), dim3(256), 0, stream>>>();
    seg_update_kernel<<<dim3(MM), dim3(256), 0, stream>>>(keys, out);
    gemm2_kernel<<<dim3(128, 4), dim3(256), 0, stream>>>(keys, out);
    loss_kernel<<<dim3(NQ), dim3(256), 0, stream>>>(keys);
    finalize_kernel<<<dim3(1), dim3(64), 0, stream>>>(out);
}